// Round 8
// baseline (45.538 us; speedup 1.0000x reference)
//
#include <hip/hip_runtime.h>
#include <math.h>

// Diversity8: loss = mean_b( 0.3 * 0.5 * sum_{m!=n} corr(p_m[b], p_n[b]) )
// corr is scale/shift-invariant -> softmax 1/S cancels. With
// u_m[c] = exp(x_m[c]/T) - 1:  cov_mn = <u_m,u_n> - t_m t_n / C,
// corr_mn = cov_mn / sqrt(cov_mm cov_nn).
// R7 lesson: wave-per-sample = 4096 waves = max 4/SIMD; replays run from L3
// (hbm_bytes ~3e4) yet still 48us -> pure latency exposure. Fix: TWO waves
// per sample (8192 waves, 8/SIMD supply), 16 upfront loads/wave, 44 partials
// combined via 704B LDS + one barrier. Epilogue redundant on all lanes.

constexpr int NC    = 1000;
constexpr int NC4   = 250;     // float4 chunks per row
constexpr int NM    = 8;
constexpr int NPAIR = NM * (NM + 1) / 2;   // 36 (m<=n)
constexpr int NRED  = NPAIR + NM;          // 44 reduced values
constexpr float KEXP = 0.072134752044448169f;  // log2(e)/20: exp(x/20)=exp2(x*KEXP)
constexpr float INVC = 1.0f / (float)NC;

__device__ __forceinline__ float waveSum(float v) {
#pragma unroll
    for (int o = 32; o > 0; o >>= 1) v += __shfl_xor(v, o, 64);
    return v;
}
__device__ __forceinline__ double waveSumD(double v) {
#pragma unroll
    for (int o = 32; o > 0; o >>= 1) v += __shfl_xor(v, o, 64);
    return v;
}
// triangular index for m<=n, NM=8; constant-folds under full unroll
__device__ __forceinline__ constexpr int tidx(int m, int n) {
    return m * (2 * NM - m + 1) / 2 + (n - m);
}

__global__ __launch_bounds__(256) void div8_main(
    const float* __restrict__ in0, const float* __restrict__ in1,
    const float* __restrict__ in2, const float* __restrict__ in3,
    const float* __restrict__ in4, const float* __restrict__ in5,
    const float* __restrict__ in6, const float* __restrict__ in7,
    float* __restrict__ part, int B)
{
    const int wid  = threadIdx.x >> 6;   // 0..3
    const int lane = threadIdx.x & 63;
    const int half = wid & 1;            // class-half handled by this wave
    const int sloc = wid >> 1;           // sample slot within block (0,1)
    const int braw = blockIdx.x * 2 + sloc;
    const bool bok = braw < B;
    const int b    = bok ? braw : (B - 1);   // clamp (all waves run: barrier safety)

    const float4* p4[NM] = {
        reinterpret_cast<const float4*>(in0 + (size_t)b * NC),
        reinterpret_cast<const float4*>(in1 + (size_t)b * NC),
        reinterpret_cast<const float4*>(in2 + (size_t)b * NC),
        reinterpret_cast<const float4*>(in3 + (size_t)b * NC),
        reinterpret_cast<const float4*>(in4 + (size_t)b * NC),
        reinterpret_cast<const float4*>(in5 + (size_t)b * NC),
        reinterpret_cast<const float4*>(in6 + (size_t)b * NC),
        reinterpret_cast<const float4*>(in7 + (size_t)b * NC) };

    // half 0: chunks {0,1} -> f4 idx lane, 64+lane (all valid)
    // half 1: chunks {2,3} -> f4 idx 128+lane, 192+lane (valid lane<58)
    const bool v1 = (half == 0) || (lane < NC4 - 3 * 64);
    const int  i0 = half ? (128 + lane) : lane;
    const int  i1 = half ? (v1 ? 192 + lane : NC4 - 1) : (64 + lane);
    const float m1 = v1 ? 1.f : 0.f;

    // ---- all 16 loads issued upfront (one memory round-trip) ----
    float4 A[NM], Bv[NM];
#pragma unroll
    for (int m = 0; m < NM; ++m) A[m]  = p4[m][i0];
#pragma unroll
    for (int m = 0; m < NM; ++m) Bv[m] = p4[m][i1];

    // ---- exp in place: u = exp2(v*K) - 1 (masked for pad lanes) ----
#pragma unroll
    for (int m = 0; m < NM; ++m) {
        A[m].x  = exp2f(A[m].x * KEXP) - 1.f;
        A[m].y  = exp2f(A[m].y * KEXP) - 1.f;
        A[m].z  = exp2f(A[m].z * KEXP) - 1.f;
        A[m].w  = exp2f(A[m].w * KEXP) - 1.f;
        Bv[m].x = (exp2f(Bv[m].x * KEXP) - 1.f) * m1;
        Bv[m].y = (exp2f(Bv[m].y * KEXP) - 1.f) * m1;
        Bv[m].z = (exp2f(Bv[m].z * KEXP) - 1.f) * m1;
        Bv[m].w = (exp2f(Bv[m].w * KEXP) - 1.f) * m1;
    }

    // ---- lane-local Gram: 36 pair-products + 8 sums over 8 element slots --
    float D[NPAIR], t[NM];
#pragma unroll
    for (int k = 0; k < NPAIR; ++k) D[k] = 0.f;
#pragma unroll
    for (int m = 0; m < NM; ++m) t[m] = 0.f;

#pragma unroll
    for (int s = 0; s < 8; ++s) {
        float us[NM];
#pragma unroll
        for (int m = 0; m < NM; ++m) {
            us[m] = (s == 0) ? A[m].x  : (s == 1) ? A[m].y
                  : (s == 2) ? A[m].z  : (s == 3) ? A[m].w
                  : (s == 4) ? Bv[m].x : (s == 5) ? Bv[m].y
                  : (s == 6) ? Bv[m].z : Bv[m].w;
        }
#pragma unroll
        for (int m = 0; m < NM; ++m) {
            t[m] += us[m];
#pragma unroll
            for (int n = m; n < NM; ++n)
                D[tidx(m, n)] = fmaf(us[m], us[n], D[tidx(m, n)]);
        }
    }

    // ---- one batch of 44 independent butterflies (results broadcast) ----
#pragma unroll
    for (int k = 0; k < NPAIR; ++k) D[k] = waveSum(D[k]);
#pragma unroll
    for (int m = 0; m < NM; ++m) t[m] = waveSum(t[m]);

    // ---- combine the two class-halves through LDS ----
    __shared__ float comb[2][2][NRED];   // [sample][half][value]
    if (lane == 0) {
#pragma unroll
        for (int k = 0; k < NPAIR; ++k) comb[sloc][half][k] = D[k];
#pragma unroll
        for (int m = 0; m < NM; ++m) comb[sloc][half][NPAIR + m] = t[m];
    }
    __syncthreads();

    // ---- epilogue, redundant on all 64 lanes of both waves of this sample --
    float Gd[NPAIR], Gt[NM];
#pragma unroll
    for (int k = 0; k < NPAIR; ++k) Gd[k] = comb[sloc][0][k] + comb[sloc][1][k];
#pragma unroll
    for (int m = 0; m < NM; ++m)
        Gt[m] = comb[sloc][0][NPAIR + m] + comb[sloc][1][NPAIR + m];

    float rm[NM];
#pragma unroll
    for (int m = 0; m < NM; ++m) {
        // cov_mm: D_mm ~ 2.5, correction ~ 0.0016 -> no cancellation
        float q = fmaf(-Gt[m] * INVC, Gt[m], Gd[tidx(m, m)]);
        rm[m] = 1.0f / sqrtf(q);
    }
    double cr = 0.0;
#pragma unroll
    for (int m = 0; m < NM; ++m)
#pragma unroll
        for (int n = m + 1; n < NM; ++n) {
            float cov = fmaf(-Gt[m] * INVC, Gt[n], Gd[tidx(m, n)]);
            cr += (double)(cov * rm[m] * rm[n]);
        }
    if (half == 0 && lane == 0 && bok)
        part[b] = (float)(2.0 * cr);     // = sum_{m!=n} corr_mn for sample b
}

__global__ __launch_bounds__(256) void div8_final(
    const float* __restrict__ part, float* __restrict__ out, int B)
{
    const int t = threadIdx.x;
    double acc = 0.0;
    for (int i = t; i < B; i += 256) acc += (double)part[i];  // fixed order: deterministic
    acc = waveSumD(acc);
    __shared__ double redd[4];
    if ((t & 63) == 0) redd[t >> 6] = acc;
    __syncthreads();
    if (t == 0) {
        double tot = (redd[0] + redd[1]) + (redd[2] + redd[3]);
        // loss = mean( 0.3 * 0.5 * cross_b )
        out[0] = (float)(tot * (0.5 * 0.3 / (double)B));
    }
}

extern "C" void kernel_launch(void* const* d_in, const int* in_sizes, int n_in,
                              void* d_out, int out_size, void* d_ws, size_t ws_size,
                              hipStream_t stream)
{
    const float* a0 = (const float*)d_in[0];
    const float* a1 = (const float*)d_in[1];
    const float* a2 = (const float*)d_in[2];
    const float* a3 = (const float*)d_in[3];
    const float* a4 = (const float*)d_in[4];
    const float* a5 = (const float*)d_in[5];
    const float* a6 = (const float*)d_in[6];
    const float* a7 = (const float*)d_in[7];
    const int B = in_sizes[0] / NC;   // 4096

    float* part = (float*)d_ws;       // B floats of scratch

    const int grid = (B + 1) / 2;     // 2 samples per block, 2 waves per sample
    div8_main<<<grid, 256, 0, stream>>>(a0, a1, a2, a3, a4, a5, a6, a7, part, B);
    div8_final<<<1, 256, 0, stream>>>(part, (float*)d_out, B);
}

// Round 9
// 36.204 us; speedup vs baseline: 1.2578x; 1.2578x over previous
//
#include <hip/hip_runtime.h>
#include <math.h>

// Diversity8: loss = mean_b( 0.3 * 0.5 * sum_{m!=n} corr(p_m[b], p_n[b]) )
// corr is scale/shift-invariant -> softmax 1/S cancels. With
// u_m[c] = exp(x_m[c]/T) - 1:  cov_mn = <u_m,u_n> - t_m t_n / C,
// corr_mn = cov_mn / sqrt(cov_mm cov_nn).
// One wave per sample; 44 lane-local partials (36 Gram + 8 sums); reductions
// via DPP (VALU pipe, no LDS crossbar): row_shr 1/2/4/8 + row_bcast 15/31,
// then readlane(63) broadcasts through an SGPR. Loads pipelined 1 chunk ahead,
// pinned with sched_barrier(0) so the compiler can't sink them.
// R8 lesson: 264 shfl_xor/wave on the shared LDS pipe was ~14us chip-wide at
// 8192 waves; DPP reductions ride the 4x-wider VALU pipe instead.

constexpr int NC    = 1000;
constexpr int NC4   = 250;     // float4 chunks per row
constexpr int NM    = 8;
constexpr int NPAIR = NM * (NM + 1) / 2;   // 36 (m<=n)
constexpr float KEXP = 0.072134752044448169f;  // log2(e)/20: exp(x/20)=exp2(x*KEXP)
constexpr float INVC = 1.0f / (float)NC;

// ---- full-wave (64-lane) sum on the VALU pipe; result broadcast to all lanes
__device__ __forceinline__ float dppSumBcast(float v) {
    // row_shr:1,2,4,8 -> lane 15/31/47/63 hold their 16-lane row sums
    v += __int_as_float(__builtin_amdgcn_update_dpp(
            0, __float_as_int(v), 0x111, 0xf, 0xf, false));
    v += __int_as_float(__builtin_amdgcn_update_dpp(
            0, __float_as_int(v), 0x112, 0xf, 0xf, false));
    v += __int_as_float(__builtin_amdgcn_update_dpp(
            0, __float_as_int(v), 0x114, 0xf, 0xf, false));
    v += __int_as_float(__builtin_amdgcn_update_dpp(
            0, __float_as_int(v), 0x118, 0xf, 0xf, false));
    // row_bcast:15 -> lane31 += lane15, lane63 += lane47
    v += __int_as_float(__builtin_amdgcn_update_dpp(
            0, __float_as_int(v), 0x142, 0xf, 0xf, false));
    // row_bcast:31 -> lane63 += lane31  (lane 63 = full sum)
    v += __int_as_float(__builtin_amdgcn_update_dpp(
            0, __float_as_int(v), 0x143, 0xf, 0xf, false));
    return __int_as_float(__builtin_amdgcn_readlane(__float_as_int(v), 63));
}

__device__ __forceinline__ double waveSumD(double v) {
#pragma unroll
    for (int o = 32; o > 0; o >>= 1) v += __shfl_xor(v, o, 64);
    return v;
}
// triangular index for m<=n, NM=8; constant-folds under full unroll
__device__ __forceinline__ constexpr int tidx(int m, int n) {
    return m * (2 * NM - m + 1) / 2 + (n - m);
}

__global__ __launch_bounds__(256) void div8_main(
    const float* __restrict__ in0, const float* __restrict__ in1,
    const float* __restrict__ in2, const float* __restrict__ in3,
    const float* __restrict__ in4, const float* __restrict__ in5,
    const float* __restrict__ in6, const float* __restrict__ in7,
    float* __restrict__ part, int B)
{
    const int wid  = threadIdx.x >> 6;
    const int lane = threadIdx.x & 63;
    const int b    = blockIdx.x * 4 + wid;   // one wave per sample; no barriers
    if (b >= B) return;
    const bool act3 = lane < (NC4 - 3 * 64); // lane < 58: chunk j=3 valid

    const float4* p4[NM] = {
        reinterpret_cast<const float4*>(in0 + (size_t)b * NC),
        reinterpret_cast<const float4*>(in1 + (size_t)b * NC),
        reinterpret_cast<const float4*>(in2 + (size_t)b * NC),
        reinterpret_cast<const float4*>(in3 + (size_t)b * NC),
        reinterpret_cast<const float4*>(in4 + (size_t)b * NC),
        reinterpret_cast<const float4*>(in5 + (size_t)b * NC),
        reinterpret_cast<const float4*>(in6 + (size_t)b * NC),
        reinterpret_cast<const float4*>(in7 + (size_t)b * NC) };

    // chunk addresses + masks (branch-free pads: clamped VALID address, x0)
    const int   idx[4] = { lane, lane + 64, lane + 128, act3 ? lane + 192 : NC4 - 1 };
    const float msk[4] = { 1.f, 1.f, 1.f, act3 ? 1.f : 0.f };

    float D[NPAIR];            // sum_c u_m u_n  (m<=n)
    float t[NM];               // sum_c u_m
#pragma unroll
    for (int k = 0; k < NPAIR; ++k) D[k] = 0.f;
#pragma unroll
    for (int m = 0; m < NM; ++m) t[m] = 0.f;

    // ---- pipelined chunk loop: loads for j+1 issued BEFORE computing j,
    //      pinned by sched_barrier so they can't be sunk ----
    float4 cur[NM], nxt[NM];
#pragma unroll
    for (int m = 0; m < NM; ++m) cur[m] = p4[m][idx[0]];

#pragma unroll
    for (int j = 0; j < 4; ++j) {
        if (j < 3) {
#pragma unroll
            for (int m = 0; m < NM; ++m) nxt[m] = p4[m][idx[j + 1]];
        }
        __builtin_amdgcn_sched_barrier(0);   // loads above stay above
        // exp in-place: u = (exp2(v*K) - 1) * msk   (clamped addr -> finite)
        const float mj = msk[j];
#pragma unroll
        for (int m = 0; m < NM; ++m) {
            cur[m].x = (exp2f(cur[m].x * KEXP) - 1.f) * mj;
            cur[m].y = (exp2f(cur[m].y * KEXP) - 1.f) * mj;
            cur[m].z = (exp2f(cur[m].z * KEXP) - 1.f) * mj;
            cur[m].w = (exp2f(cur[m].w * KEXP) - 1.f) * mj;
        }
        // 44 partials per scalar component (static indexing only)
#pragma unroll
        for (int comp = 0; comp < 4; ++comp) {
            float us[NM];
#pragma unroll
            for (int m = 0; m < NM; ++m)
                us[m] = (comp == 0) ? cur[m].x : (comp == 1) ? cur[m].y
                      : (comp == 2) ? cur[m].z : cur[m].w;
#pragma unroll
            for (int m = 0; m < NM; ++m) {
                t[m] += us[m];
#pragma unroll
                for (int n = m; n < NM; ++n)
                    D[tidx(m, n)] = fmaf(us[m], us[n], D[tidx(m, n)]);
            }
        }
        if (j < 3) {
#pragma unroll
            for (int m = 0; m < NM; ++m) cur[m] = nxt[m];
        }
    }

    // ---- 44 independent DPP reductions (VALU pipe; results broadcast) ----
#pragma unroll
    for (int k = 0; k < NPAIR; ++k) D[k] = dppSumBcast(D[k]);
#pragma unroll
    for (int m = 0; m < NM; ++m) t[m] = dppSumBcast(t[m]);

    // ---- epilogue, identical on all 64 lanes (broadcast scalars) ----
    float rm[NM];
#pragma unroll
    for (int m = 0; m < NM; ++m) {
        // cov_mm: D_mm ~ 2.5, correction ~ 0.0016 -> no cancellation
        float q = fmaf(-t[m] * INVC, t[m], D[tidx(m, m)]);
        rm[m] = 1.0f / sqrtf(q);
    }
    double cr = 0.0;
#pragma unroll
    for (int m = 0; m < NM; ++m)
#pragma unroll
        for (int n = m + 1; n < NM; ++n) {
            float cov = fmaf(-t[m] * INVC, t[n], D[tidx(m, n)]);
            cr += (double)(cov * rm[m] * rm[n]);
        }
    if (lane == 0) part[b] = (float)(2.0 * cr);  // = sum_{m!=n} corr_mn
}

__global__ __launch_bounds__(256) void div8_final(
    const float* __restrict__ part, float* __restrict__ out, int B)
{
    const int t = threadIdx.x;
    double acc = 0.0;
    for (int i = t; i < B; i += 256) acc += (double)part[i];  // fixed order: deterministic
    acc = waveSumD(acc);
    __shared__ double redd[4];
    if ((t & 63) == 0) redd[t >> 6] = acc;
    __syncthreads();
    if (t == 0) {
        double tot = (redd[0] + redd[1]) + (redd[2] + redd[3]);
        // loss = mean( 0.3 * 0.5 * cross_b )
        out[0] = (float)(tot * (0.5 * 0.3 / (double)B));
    }
}

extern "C" void kernel_launch(void* const* d_in, const int* in_sizes, int n_in,
                              void* d_out, int out_size, void* d_ws, size_t ws_size,
                              hipStream_t stream)
{
    const float* a0 = (const float*)d_in[0];
    const float* a1 = (const float*)d_in[1];
    const float* a2 = (const float*)d_in[2];
    const float* a3 = (const float*)d_in[3];
    const float* a4 = (const float*)d_in[4];
    const float* a5 = (const float*)d_in[5];
    const float* a6 = (const float*)d_in[6];
    const float* a7 = (const float*)d_in[7];
    const int B = in_sizes[0] / NC;   // 4096

    float* part = (float*)d_ws;       // B floats of scratch

    const int grid = (B + 3) / 4;     // 4 samples (waves) per block
    div8_main<<<grid, 256, 0, stream>>>(a0, a1, a2, a3, a4, a5, a6, a7, part, B);
    div8_final<<<1, 256, 0, stream>>>(part, (float*)d_out, B);
}